// Round 5
// baseline (72.520 us; speedup 1.0000x reference)
//
#include <hip/hip_runtime.h>
#include <math.h>

// B=16, S=8192, D=256. out[b,s,d] = y[b,s]*W[d] + bias[d],
// y = lowpass(x) keep |f|<2048, x = ids/255.
// Parity split: y[2i]   = 0.5*x_e[i] + sum_j Kp[j]*x_o[(i-1-j) mod 4096]
//               y[2i+1] = 0.5*x_o[i] + sum_j Kp[j]*x_e[(i-j)   mod 4096]
// Kp[j] = (-1)^j * cot(pi*(2j+1)/8192) / 8192.
// Stage 1 (conv): grid (row, outseg, tapseg) -> partial sums in ws.
// Stage 2 (write): sum 4 partials + center tap, broadcast over D.

#define SEQ    8192
#define HSEQ   4096
#define DIM    256
#define NBAT   16

#define TBLF   1280        // logical floats per parity window
#define TO_B   1616        // phys float offset of To (byte 6464 == 64 mod 128)
#define TABTOT 3216
#define REDW   132         // reduction row stride (128 + 4 pad)

__device__ __forceinline__ int physf(int g) { return g + ((g >> 4) << 2); }

__global__ __launch_bounds__(256)
void ktab_kernel(float* __restrict__ kt) {
    int j = blockIdx.x * 256 + threadIdx.x;    // delta = 2j+1
    if (j >= HSEQ) return;
    int delta = 2 * j + 1;
    double ang = M_PI * (double)delta / (double)SEQ;
    double v = (cos(ang) / sin(ang)) / (double)SEQ;
    if (j & 1) v = -v;
    kt[j] = (float)v;
}

// 3 waves/EU min => VGPR cap ~170: lets the compiler keep xw[48]+kw[32]+acc[16]
// (~115 regs) live instead of re-loading operands inside the FMA stream.
__global__ __launch_bounds__(256, 3)
void conv_kernel(const int* __restrict__ ids,
                 const float* __restrict__ kd,
                 float* __restrict__ ypart) {
    __shared__ float ts[TABTOT];       // Te @0, To @TO_B (pad-swizzled)
    __shared__ float red[32 * REDW];   // [pm 32][slice 8 * 16] partials

    const int t   = threadIdx.x;
    const int blk = blockIdx.x;
    const int g   = blk & 3;           // tap segment (1024 taps)
    const int o   = (blk >> 2) & 15;   // output segment (256 packed per parity)
    const int r   = blk >> 6;          // batch row
    const int i0  = o << 8;

    // ---- stage windows ----
    const int* row = ids + r * SEQ;
    const float inv255 = 1.0f / 255.0f;
    const int lo_o = i0 - (g << 10) - 1024;   // To[u] = x_o[(u+lo_o)&4095]
    const int lo_e = lo_o + 1;                // Te[u] = x_e[(u+lo_e)&4095]
    for (int u = t; u < TBLF; u += 256) {
        int se = (u + lo_e) & (HSEQ - 1);
        int so = (u + lo_o) & (HSEQ - 1);
        int ph = physf(u);
        ts[ph]        = (float)row[2 * se]     * inv255;   // Te
        ts[TO_B + ph] = (float)row[2 * so + 1] * inv255;   // To
    }
    __syncthreads();

    // lane roles: w = wave (256-tap slice), h = 128-tap half, p = parity, m = out group
    const int w = t >> 6, l = t & 63;
    const int h = l >> 5, p = (l >> 4) & 1, m = l & 15;
    const float* tp = ts + (p ? 0 : TO_B);   // even outputs read x_odd, odd read x_even
    const int Jl0 = (w << 8) + (h << 7);

    float acc[16];
    #pragma unroll
    for (int q = 0; q < 16; ++q) acc[q] = 0.f;

    #pragma unroll 1
    for (int c = 0; c < 4; ++c) {
        const int Jloc = Jl0 + (c << 5);
        const int us   = (m << 4) + 992 - Jloc;        // window start, mult of 16
        const float4* xb = (const float4*)(tp + physf(us));
        float xw[48];
        #pragma unroll
        for (int q = 0; q < 12; ++q) {
            const float4 v = xb[q + (q >> 2)];          // phys quads skip every 5th
            xw[4*q+0] = v.x; xw[4*q+1] = v.y; xw[4*q+2] = v.z; xw[4*q+3] = v.w;
        }
        const float4* kb = (const float4*)(kd + (g << 10) + Jloc);
        float kw[32];
        #pragma unroll
        for (int q = 0; q < 8; ++q) {
            const float4 v = kb[q];
            kw[4*q+0] = v.x; kw[4*q+1] = v.y; kw[4*q+2] = v.z; kw[4*q+3] = v.w;
        }
        // acc[q] += Kp[J+jj] * table[us + 31 - jj + q]
        #pragma unroll
        for (int jj = 0; jj < 32; ++jj) {
            const float kj = kw[jj];
            #pragma unroll
            for (int q = 0; q < 16; ++q)
                acc[q] = fmaf(kj, xw[31 - jj + q], acc[q]);
        }
    }

    // ---- partial scatter + cross-slice reduction ----
    const int sl = (w << 1) | h;
    float4* rb = (float4*)(red + ((p << 4) | m) * REDW + (sl << 4));
    rb[0] = make_float4(acc[0],  acc[1],  acc[2],  acc[3]);
    rb[1] = make_float4(acc[4],  acc[5],  acc[6],  acc[7]);
    rb[2] = make_float4(acc[8],  acc[9],  acc[10], acc[11]);
    rb[3] = make_float4(acc[12], acc[13], acc[14], acc[15]);
    __syncthreads();

    const int m2 = t >> 4, r2 = t & 15;
    float se_ = 0.f, so_ = 0.f;
    #pragma unroll
    for (int s = 0; s < 8; ++s) {
        se_ += red[m2 * REDW + (s << 4) + r2];          // p=0 (even s)
        so_ += red[(16 + m2) * REDW + (s << 4) + r2];   // p=1 (odd s)
    }
    float2 v2; v2.x = se_; v2.y = so_;
    *(float2*)(ypart + (g * NBAT + r) * SEQ + ((i0 + (m2 << 4) + r2) << 1)) = v2;
}

__global__ __launch_bounds__(256)
void write_kernel(const int* __restrict__ ids,
                  const float* __restrict__ ypart,
                  const float* __restrict__ W,
                  const float* __restrict__ bias,
                  float* __restrict__ out) {
    __shared__ float ys[256];
    const int t  = threadIdx.x;
    const int r  = blockIdx.x >> 5;
    const int s0 = (blockIdx.x & 31) << 8;
    const int s  = s0 + t;

    float v = 0.f;
    #pragma unroll
    for (int g = 0; g < 4; ++g) v += ypart[(g * NBAT + r) * SEQ + s];
    v += 0.5f * (float)ids[r * SEQ + s] * (1.0f / 255.0f);
    ys[t] = v;
    __syncthreads();

    const int d = (t & 63) * 4;
    const float4 w4 = *(const float4*)(W + d);
    const float4 b4 = *(const float4*)(bias + d);
    float* orow = out + ((long long)r * SEQ + s0) * DIM;
    for (int i = t >> 6; i < 256; i += 4) {
        const float y = ys[i];
        float4 o4;
        o4.x = fmaf(y, w4.x, b4.x);
        o4.y = fmaf(y, w4.y, b4.y);
        o4.z = fmaf(y, w4.z, b4.z);
        o4.w = fmaf(y, w4.w, b4.w);
        *(float4*)(orow + (long long)i * DIM + d) = o4;
    }
}

extern "C" void kernel_launch(void* const* d_in, const int* in_sizes, int n_in,
                              void* d_out, int out_size, void* d_ws, size_t ws_size,
                              hipStream_t stream) {
    const int*   ids  = (const int*)d_in[0];
    const float* W    = (const float*)d_in[1];
    const float* bias = (const float*)d_in[2];
    float* out   = (float*)d_out;
    float* kt    = (float*)d_ws;            // 4096 floats
    float* ypart = (float*)d_ws + HSEQ;     // 4*16*8192 floats = 2 MB

    ktab_kernel<<<HSEQ / 256, 256, 0, stream>>>(kt);
    conv_kernel<<<NBAT * 16 * 4, 256, 0, stream>>>(ids, kt, ypart);
    write_kernel<<<NBAT * (SEQ / 256), 256, 0, stream>>>(ids, ypart, W, bias, out);
}

// Round 7
// 50.379 us; speedup vs baseline: 1.4395x; 1.4395x over previous
//
#include <hip/hip_runtime.h>
#include <hip/hip_bf16.h>
#include <math.h>

// B=16, S=8192, D=256. out[b,s,d] = y[b,s]*W[d] + bias[d],
// y = lowpass(x), keep |f|<2048, x = ids/255.
// Parity split: y[2i]   = 0.5*x_e[i] + sum_j Kp[j]*x_o[(i-1-j) mod 4096]
//               y[2i+1] = 0.5*x_o[i] + sum_j Kp[j]*x_e[(i-j)   mod 4096]
// Kp[j] = (-1)^j * cot(pi*(2j+1)/8192)/8192.
// MFMA form per 16-output group (i0) and parity P, over tap blocks j0:
//   C[o][b] += sum_tau Ktil[j0+o+tau] * R_P[b][(4096 - i0) + j0 + tau]
// with Ktil[u] = Kp[u mod 4096]/255 (bf16), R tables = batch rows of
// index-reversed x-parity sequences in raw id units (exact bf16).

#define SEQ    8192
#define HSEQ   4096
#define DIM    256
#define NBAT   16

#define KROW   4128                    // Ktil copy length (covers j0+obase+31)
#define RROW   8224                    // reversed-table length (covers u in [16,8191])
#define KS_OFF 0                       // 8 copies * 4128 * 2B = 66048
#define RO_OFF 66048                   // 16 * 8224 * 2B = 263168
#define RE_OFF 329216                  // 16 * 8224 * 2B = 263168
#define YPK_OFF 592384                 // 8192*16 f32 = 512KB

typedef __attribute__((ext_vector_type(8))) short short8v;
typedef __attribute__((ext_vector_type(4))) float f32x4;

__device__ __forceinline__ short bfbits(float f) {
    __hip_bfloat16 h = __float2bfloat16(f);
    return *(short*)&h;
}

__global__ __launch_bounds__(256)
void prep_kernel(const int* __restrict__ ids, unsigned char* __restrict__ ws8) {
    short* Ks = (short*)(ws8 + KS_OFF);
    short* Ro = (short*)(ws8 + RO_OFF);
    short* Re = (short*)(ws8 + RE_OFF);
    const int idx = blockIdx.x * 256 + threadIdx.x;
    const int n   = gridDim.x * 256;

    // Ktil shift-copies: Ks[r][u] = Kp[(u+r) mod 4096] / 255   (bf16)
    for (int i = idx; i < 8 * KROW; i += n) {
        int r = i / KROW, u = i - r * KROW;
        int j = (u + r) & (HSEQ - 1);
        double dj  = 2.0 * j + 1.0;
        double ang = M_PI * dj / 8192.0;
        double v = (cos(ang) / sin(ang)) / (8192.0 * 255.0);
        if (j & 1) v = -v;
        Ks[i] = bfbits((float)v);
    }
    // Reversed parity tables (raw id values, exact in bf16):
    //  Ro[b][u] = x_o[(-1-u) mod 4096] = ids[b][2*((4095-u)&4095)+1]
    //  Re[b][u] = x_e[(-u)   mod 4096] = ids[b][2*((4096-u)&4095)]
    for (int i = idx; i < NBAT * RROW; i += n) {
        int b = i / RROW, u = i - b * RROW;
        int mo = (4095 - u) & (HSEQ - 1);
        int me = (4096 - u) & (HSEQ - 1);
        const int* row = ids + b * SEQ;
        Ro[i] = bfbits((float)row[2 * mo + 1]);
        Re[i] = bfbits((float)row[2 * me]);
    }
}

__global__ __launch_bounds__(64)
void conv_kernel(const unsigned char* __restrict__ ws8,
                 float* __restrict__ ypk) {
    const int bid = blockIdx.x;        // 0..511
    const int P   = bid & 1;           // 0 = even outputs, 1 = odd outputs
    const int grp = bid >> 1;          // 0..255
    const int i0  = grp << 4;
    const int l   = threadIdx.x;       // one wave
    const int oc  = l & 15;            // A-row o / B-col b
    const int koff = l >> 4;           // k-group 0..3

    // A: Ks[oc&7][ (oc&8) + 8*koff + j0 + e ]  -> 16B-aligned dwordx4
    const short* Ap = (const short*)(ws8 + KS_OFF)
                      + (oc & 7) * KROW + ((oc & 8) + koff * 8);
    // B: R_P[oc][ (4096 - i0) + 8*koff + j0 + e ] -> 16B-aligned dwordx4
    const short* Rp = (const short*)(ws8 + (P ? RE_OFF : RO_OFF))
                      + oc * RROW + (HSEQ - i0) + koff * 8;

    f32x4 acc = {0.f, 0.f, 0.f, 0.f};
    #pragma unroll 8
    for (int j0 = 0; j0 < HSEQ; j0 += 32) {
        short8v a  = *(const short8v*)(Ap + j0);
        short8v bv = *(const short8v*)(Rp + j0);
        acc = __builtin_amdgcn_mfma_f32_16x16x32_bf16(a, bv, acc, 0, 0, 0);
    }

    // C layout (m89): col = lane&15 (= batch), row = (lane>>4)*4 + q (= o)
    float* yo = ypk + (P * HSEQ + i0) * NBAT;
    #pragma unroll
    for (int q = 0; q < 4; ++q) {
        int o = koff * 4 + q;
        yo[o * NBAT + oc] = acc[q];
    }
}

__global__ __launch_bounds__(256)
void write_kernel(const int* __restrict__ ids,
                  const float* __restrict__ ypk,
                  const float* __restrict__ W,
                  const float* __restrict__ bias,
                  float* __restrict__ out) {
    __shared__ float ys[256];
    const int t  = threadIdx.x;
    const int r  = blockIdx.x >> 5;
    const int s0 = (blockIdx.x & 31) << 8;
    const int s  = s0 + t;

    float v = ypk[((s & 1) * HSEQ + (s >> 1)) * NBAT + r];
    v += (float)ids[r * SEQ + s] * (0.5f / 255.0f);
    ys[t] = v;
    __syncthreads();

    const int d = (t & 63) * 4;
    const float4 w4 = *(const float4*)(W + d);
    const float4 b4 = *(const float4*)(bias + d);
    float* orow = out + ((long long)r * SEQ + s0) * DIM;
    for (int i = t >> 6; i < 256; i += 4) {
        const float y = ys[i];
        f32x4 o4;
        o4.x = fmaf(y, w4.x, b4.x);
        o4.y = fmaf(y, w4.y, b4.y);
        o4.z = fmaf(y, w4.z, b4.z);
        o4.w = fmaf(y, w4.w, b4.w);
        __builtin_nontemporal_store(o4, (f32x4*)(orow + (long long)i * DIM + d));
    }
}

extern "C" void kernel_launch(void* const* d_in, const int* in_sizes, int n_in,
                              void* d_out, int out_size, void* d_ws, size_t ws_size,
                              hipStream_t stream) {
    const int*   ids  = (const int*)d_in[0];
    const float* W    = (const float*)d_in[1];
    const float* bias = (const float*)d_in[2];
    float* out = (float*)d_out;
    unsigned char* ws8 = (unsigned char*)d_ws;
    float* ypk = (float*)(ws8 + YPK_OFF);

    prep_kernel<<<512, 256, 0, stream>>>(ids, ws8);
    conv_kernel<<<512, 64, 0, stream>>>(ws8, ypk);
    write_kernel<<<NBAT * (SEQ / 256), 256, 0, stream>>>(ids, ypk, W, bias, out);
}